// Round 7
// baseline (341.354 us; speedup 1.0000x reference)
//
#include <hip/hip_runtime.h>

#define HH 2048
#define WW 2048
constexpr float DT = 0.01f;
constexpr float VISC = 0.001f;

// ---------------------------------------------------------------- bilerp ----
__device__ __forceinline__ float bilerp(const float* __restrict__ f, int h, int w,
                                        float y, float x) {
    int x0 = (int)floorf(x);
    int y0 = (int)floorf(y);
    int x1 = x0 + 1, y1 = y0 + 1;
    x0 = min(max(x0, 0), w - 1);
    x1 = min(max(x1, 0), w - 1);
    y0 = min(max(y0, 0), h - 1);
    y1 = min(max(y1, 0), h - 1);
    float x0f = (float)x0, x1f = (float)x1, y0f = (float)y0, y1f = (float)y1;
    float wa = (x1f - x) * (y1f - y);
    float wb = (x - x0f) * (y1f - y);
    float wc = (x1f - x) * (y - y0f);
    float wd = (x - x0f) * (y - y0f);
    return wa * f[y0 * w + x0] + wb * f[y0 * w + x1] +
           wc * f[y1 * w + x0] + wd * f[y1 * w + x1];
}

// ------------------------------------------------- diffuse helpers (exact) --
__device__ __forceinline__ float udiff_at(const float* __restrict__ u, int i, int j) {
    // u: (HH+1, WW)
    int jm = max(j - 1, 0), jp = min(j + 1, WW - 1);
    int im = max(i - 1, 0), ip = min(i + 1, HH);
    float c = u[(size_t)i * WW + j];
    float lap = u[(size_t)im * WW + j] + u[(size_t)ip * WW + j] +
                u[(size_t)i * WW + jm] + u[(size_t)i * WW + jp] - 4.0f * c;
    return c + (DT * VISC) * lap;
}

__device__ __forceinline__ float vf_(const float* __restrict__ v,
                                     const float* __restrict__ den, int i, int j) {
    float val = v[(size_t)i * (WW + 1) + j];
    if (j < WW) val += DT * (den[(size_t)i * WW + j] * 0.1f);
    return val;
}

__device__ __forceinline__ float vdiff_at(const float* __restrict__ v,
                                          const float* __restrict__ den, int i, int j) {
    // v: (HH, WW+1)
    int jm = max(j - 1, 0), jp = min(j + 1, WW);
    int im = max(i - 1, 0), ip = min(i + 1, HH - 1);
    float c = vf_(v, den, i, j);
    float lap = vf_(v, den, im, j) + vf_(v, den, ip, j) +
                vf_(v, den, i, jm) + vf_(v, den, i, jp) - 4.0f * c;
    return c + (DT * VISC) * lap;
}

__device__ __forceinline__ float ddiff_at(const float* __restrict__ d, int i, int j) {
    int jm = max(j - 1, 0), jp = min(j + 1, WW - 1);
    int im = max(i - 1, 0), ip = min(i + 1, HH - 1);
    float c = d[(size_t)i * WW + j];
    float lap = d[(size_t)im * WW + j] + d[(size_t)ip * WW + j] +
                d[(size_t)i * WW + jm] + d[(size_t)i * WW + jp] - 4.0f * c;
    return c + (DT * (VISC * 0.1f)) * lap;
}

// ---------------------------------------------- fused front (diffuse + div) --
// One pass over u, v, den: writes diffused u, v, d AND divergence. div needs
// u_diff(i+1,j) / v_diff(i,j+1), recomputed per-thread (stencil loads are
// L1/L2 hits). Each thread handles 4 consecutive cols. Grid.y covers 2049
// rows; row 2048 is u-only. v's extra col WW is handled by the last chunk.
__global__ __launch_bounds__(256) void k_front(
    const float* __restrict__ u, const float* __restrict__ v,
    const float* __restrict__ den, float* __restrict__ ud,
    float* __restrict__ vd, float* __restrict__ dd, float* __restrict__ dv) {
    const int j0 = (blockIdx.x * 256 + threadIdx.x) * 4;
    const int i = blockIdx.y;
    if (j0 >= WW) return;

    float4 udv;
    udv.x = udiff_at(u, i, j0 + 0);
    udv.y = udiff_at(u, i, j0 + 1);
    udv.z = udiff_at(u, i, j0 + 2);
    udv.w = udiff_at(u, i, j0 + 3);
    *reinterpret_cast<float4*>(ud + (size_t)i * WW + j0) = udv;

    if (i < HH) {
        float4 vdv;
        vdv.x = vdiff_at(v, den, i, j0 + 0);
        vdv.y = vdiff_at(v, den, i, j0 + 1);
        vdv.z = vdiff_at(v, den, i, j0 + 2);
        vdv.w = vdiff_at(v, den, i, j0 + 3);
        const size_t vb = (size_t)i * (WW + 1) + j0;
        vd[vb + 0] = vdv.x; vd[vb + 1] = vdv.y;
        vd[vb + 2] = vdv.z; vd[vb + 3] = vdv.w;
        const float vnext = vdiff_at(v, den, i, j0 + 4);  // col j0+4 <= WW, valid
        if (j0 + 4 == WW) vd[vb + 4] = vnext;             // v's last column

        float4 ddv;
        ddv.x = ddiff_at(den, i, j0 + 0);
        ddv.y = ddiff_at(den, i, j0 + 1);
        ddv.z = ddiff_at(den, i, j0 + 2);
        ddv.w = ddiff_at(den, i, j0 + 3);
        *reinterpret_cast<float4*>(dd + (size_t)i * WW + j0) = ddv;

        // div = (u1 - u0 + v1 - v0) / DT, left-to-right order
        float4 dvv;
        dvv.x = (udiff_at(u, i + 1, j0 + 0) - udv.x + vdv.y - vdv.x) / DT;
        dvv.y = (udiff_at(u, i + 1, j0 + 1) - udv.y + vdv.z - vdv.y) / DT;
        dvv.z = (udiff_at(u, i + 1, j0 + 2) - udv.z + vdv.w - vdv.z) / DT;
        dvv.w = (udiff_at(u, i + 1, j0 + 3) - udv.w + vnext - vdv.w) / DT;
        *reinterpret_cast<float4*>(dv + (size_t)i * WW + j0) = dvv;
    }
}

// ---------------------------------------------------- fused Jacobi (K=4) ----
#define TILE 56
#define KF 4
#define LW 64

__global__ __launch_bounds__(256) void k_jacobi_fused(
    const float* __restrict__ pin_g, const float* __restrict__ div_g,
    float* __restrict__ pout_g, int first) {
    __shared__ float pA[LW * LW];
    __shared__ float pB[LW * LW];

    const int t = threadIdx.x;
    const int gx0 = blockIdx.x * TILE - KF;
    const int gy0 = blockIdx.y * TILE - KF;

    float dreg[16];

    #pragma unroll
    for (int c = 0; c < 4; ++c)
        reinterpret_cast<float4*>(pB)[c * 256 + t] = make_float4(0.f, 0.f, 0.f, 0.f);

    #pragma unroll
    for (int c = 0; c < 4; ++c) {
        const int ci = c * 256 + t;
        const int y = ci >> 4;
        const int x = (ci & 15) * 4;
        const int gy = gy0 + y;
        const int gxb = gx0 + x;
        float4 pv = make_float4(0.f, 0.f, 0.f, 0.f);
        float4 dv4 = make_float4(0.f, 0.f, 0.f, 0.f);
        const bool rowin = (gy >= 0) && (gy < HH);
        if (rowin && gxb >= 0 && gxb + 3 < WW) {
            const size_t g = (size_t)gy * WW + gxb;
            dv4 = *reinterpret_cast<const float4*>(div_g + g);
            if (!first) pv = *reinterpret_cast<const float4*>(pin_g + g);
        } else if (rowin) {
            #pragma unroll
            for (int e = 0; e < 4; ++e) {
                const int gx = gxb + e;
                if (gx >= 0 && gx < WW) {
                    const size_t g = (size_t)gy * WW + gx;
                    (&dv4.x)[e] = div_g[g];
                    if (!first) (&pv.x)[e] = pin_g[g];
                }
            }
        }
        *reinterpret_cast<float4*>(&pA[y * LW + x]) = pv;
        dreg[c * 4 + 0] = dv4.x; dreg[c * 4 + 1] = dv4.y;
        dreg[c * 4 + 2] = dv4.z; dreg[c * 4 + 3] = dv4.w;
    }
    __syncthreads();

    float* pa = pA;
    float* pb = pB;
    for (int it = 0; it < KF; ++it) {
        #pragma unroll
        for (int c = 0; c < 4; ++c) {
            const int ci = c * 256 + t;
            const int y = ci >> 4;
            const int x = (ci & 15) * 4;
            if (y >= 1 && y <= LW - 2) {
                const float4 up = *reinterpret_cast<const float4*>(&pa[(y - 1) * LW + x]);
                const float4 dn = *reinterpret_cast<const float4*>(&pa[(y + 1) * LW + x]);
                const float4 ce = *reinterpret_cast<const float4*>(&pa[y * LW + x]);
                const float lf = (x > 0)      ? pa[y * LW + x - 1] : 0.f;
                const float rt = (x + 4 < LW) ? pa[y * LW + x + 4] : 0.f;
                const int gy = gy0 + y;
                const bool rowin = (gy > 0) && (gy < HH - 1);
                const int gxb = gx0 + x;
                float4 o;
                o.x = (rowin && gxb + 0 > 0 && gxb + 0 < WW - 1 && x + 0 > 0)
                      ? 0.25f * ((((up.x + dn.x) + lf) + ce.y) - dreg[c * 4 + 0]) : 0.f;
                o.y = (rowin && gxb + 1 > 0 && gxb + 1 < WW - 1)
                      ? 0.25f * ((((up.y + dn.y) + ce.x) + ce.z) - dreg[c * 4 + 1]) : 0.f;
                o.z = (rowin && gxb + 2 > 0 && gxb + 2 < WW - 1)
                      ? 0.25f * ((((up.z + dn.z) + ce.y) + ce.w) - dreg[c * 4 + 2]) : 0.f;
                o.w = (rowin && gxb + 3 > 0 && gxb + 3 < WW - 1 && x + 3 < LW - 1)
                      ? 0.25f * ((((up.w + dn.w) + ce.z) + rt) - dreg[c * 4 + 3]) : 0.f;
                *reinterpret_cast<float4*>(&pb[y * LW + x]) = o;
            }
        }
        __syncthreads();
        float* tmp = pa; pa = pb; pb = tmp;
    }

    #pragma unroll
    for (int c = 0; c < 4; ++c) {
        const int ci = c * 256 + t;
        const int y = ci >> 4;
        const int x = (ci & 15) * 4;
        if (y >= KF && y < KF + TILE && x >= KF && x < KF + TILE) {
            const int gy = gy0 + y;
            const int gxb = gx0 + x;
            if (gy < HH) {
                if (gxb + 3 < WW) {
                    *reinterpret_cast<float4*>(pout_g + (size_t)gy * WW + gxb) =
                        *reinterpret_cast<const float4*>(&pa[y * LW + x]);
                } else {
                    #pragma unroll
                    for (int e = 0; e < 4; ++e) {
                        const int gx = gxb + e;
                        if (gx < WW) pout_g[(size_t)gy * WW + gx] = pa[y * LW + x + e];
                    }
                }
            }
        }
    }
}

// ----------------------------------------------------- fused projection -----
// u[1:-1,:] -= DT*(p[1:,:]-p[:-1,:]) ; v[:,1:-1] -= DT*(p[:,1:]-p[:,:-1])
// One kernel, grid.y = HH rows. Row i: updates u row i (if i>=1) and v row i.
__global__ __launch_bounds__(256) void k_project(
    float* __restrict__ u, float* __restrict__ v, const float* __restrict__ p) {
    const int j0 = (blockIdx.x * 256 + threadIdx.x) * 4;
    const int i = blockIdx.y;
    if (j0 >= WW) return;

    const float4 pc = *reinterpret_cast<const float4*>(p + (size_t)i * WW + j0);

    if (i >= 1) {
        const float4 pm = *reinterpret_cast<const float4*>(p + (size_t)(i - 1) * WW + j0);
        float4 uv = *reinterpret_cast<float4*>(u + (size_t)i * WW + j0);
        uv.x -= DT * (pc.x - pm.x);
        uv.y -= DT * (pc.y - pm.y);
        uv.z -= DT * (pc.z - pm.z);
        uv.w -= DT * (pc.w - pm.w);
        *reinterpret_cast<float4*>(u + (size_t)i * WW + j0) = uv;
    }

    // v cols j0..j0+3 restricted to [1, WW-1]
    const float pl = (j0 > 0) ? p[(size_t)i * WW + j0 - 1] : 0.f;
    const size_t vb = (size_t)i * (WW + 1) + j0;
    if (j0 > 0) v[vb + 0] -= DT * (pc.x - pl);
    v[vb + 1] -= DT * (pc.y - pc.x);
    v[vb + 2] -= DT * (pc.z - pc.y);
    if (j0 + 3 <= WW - 1) v[vb + 3] -= DT * (pc.w - pc.z);
}

// ---------------------------------------------------------------- advect ----
__global__ void k_advect_u(const float* __restrict__ uf, const float* __restrict__ vf,
                           float* __restrict__ out) {
    int j = blockIdx.x * blockDim.x + threadIdx.x;
    int i = blockIdx.y;
    const int h = HH + 1, w = WW;
    if (j >= w) return;
    float X = (float)j, Y = (float)i;
    float x_u = fminf(fmaxf(X + 0.5f, 0.0f), (float)(WW - 1));
    float u_i = bilerp(uf, HH + 1, WW, Y, x_u);
    float y_v = fminf(fmaxf(Y + 0.5f, 0.0f), (float)(HH - 1));
    float v_i = bilerp(vf, HH, WW + 1, y_v, X);
    float px = fminf(fmaxf(X - DT * u_i, 0.0f), (float)(w - 1));
    float py = fminf(fmaxf(Y - DT * v_i, 0.0f), (float)(h - 1));
    out[(size_t)i * w + j] = bilerp(uf, h, w, py, px);
}

__global__ void k_advect_v(const float* __restrict__ vf, const float* __restrict__ un,
                           float* __restrict__ out) {
    int j = blockIdx.x * blockDim.x + threadIdx.x;
    int i = blockIdx.y;
    const int h = HH, w = WW + 1;
    if (j >= w) return;
    float X = (float)j, Y = (float)i;
    float x_u = fminf(fmaxf(X + 0.5f, 0.0f), (float)(WW - 1));
    float u_i = bilerp(un, HH + 1, WW, Y, x_u);
    float y_v = fminf(fmaxf(Y + 0.5f, 0.0f), (float)(HH - 1));
    float v_i = bilerp(vf, HH, WW + 1, y_v, X);
    float px = fminf(fmaxf(X - DT * u_i, 0.0f), (float)(w - 1));
    float py = fminf(fmaxf(Y - DT * v_i, 0.0f), (float)(h - 1));
    out[(size_t)i * w + j] = bilerp(vf, h, w, py, px);
}

__global__ void k_advect_d(const float* __restrict__ df, const float* __restrict__ un,
                           const float* __restrict__ vn, float* __restrict__ out) {
    int j = blockIdx.x * blockDim.x + threadIdx.x;
    int i = blockIdx.y;
    const int h = HH, w = WW;
    if (j >= w) return;
    float X = (float)j, Y = (float)i;
    float x_u = fminf(fmaxf(X + 0.5f, 0.0f), (float)(WW - 1));
    float u_i = bilerp(un, HH + 1, WW, Y, x_u);
    float y_v = fminf(fmaxf(Y + 0.5f, 0.0f), (float)(HH - 1));
    float v_i = bilerp(vn, HH, WW + 1, y_v, X);
    float px = fminf(fmaxf(X - DT * u_i, 0.0f), (float)(w - 1));
    float py = fminf(fmaxf(Y - DT * v_i, 0.0f), (float)(h - 1));
    out[(size_t)i * w + j] = 0.995f * bilerp(df, h, w, py, px);
}

// ---------------------------------------------------------------- launch ----
extern "C" void kernel_launch(void* const* d_in, const int* in_sizes, int n_in,
                              void* d_out, int out_size, void* d_ws, size_t ws_size,
                              hipStream_t stream) {
    const float* u_in   = (const float*)d_in[0];
    const float* v_in   = (const float*)d_in[1];
    const float* den_in = (const float*)d_in[2];
    float* out = (float*)d_out;

    const size_t SZ_UV = (size_t)(HH + 1) * WW;
    const size_t SZ_D  = (size_t)HH * WW;

    float* ws = (float*)d_ws;
    float* uA = ws;  ws += SZ_UV;
    float* uB = ws;  ws += SZ_UV;
    float* vA = ws;  ws += SZ_UV;
    float* vB = ws;  ws += SZ_UV;
    float* dA = ws;  ws += SZ_D;
    float* dv = ws;  ws += SZ_D;
    float* p0 = ws;  ws += SZ_D;
    float* p1 = ws;  ws += SZ_D;

    dim3 blk(256, 1, 1);

    // fused diffuse(u,v,d) + divergence: 2 blocks/row, 2049 rows
    dim3 gF(WW / (256 * 4), HH + 1);  // (2, 2049)
    k_front<<<gF, blk, 0, stream>>>(u_in, v_in, den_in, uA, vA, dA, dv);

    // 20 Jacobi iterations = 5 launches x 4 fused (first starts from p=0).
    dim3 gJ((WW + TILE - 1) / TILE, (HH + TILE - 1) / TILE);  // 37 x 37
    k_jacobi_fused<<<gJ, blk, 0, stream>>>(dv /*unused*/, dv, p1, 1);
    float* pin = p1;
    float* pout = p0;
    for (int l = 1; l < 5; ++l) {
        k_jacobi_fused<<<gJ, blk, 0, stream>>>(pin, dv, pout, 0);
        float* t = pin; pin = pout; pout = t;
    }
    // final pressure in `pin`

    // fused projection
    dim3 gP(WW / (256 * 4), HH);  // (2, 2048)
    k_project<<<gP, blk, 0, stream>>>(uA, vA, pin);

    dim3 gU((WW + 255) / 256, HH + 1);
    dim3 gV((WW + 1 + 255) / 256, HH);
    dim3 gD((WW + 255) / 256, HH);
    k_advect_u<<<gU, blk, 0, stream>>>(uA, vA, uB);
    k_advect_v<<<gV, blk, 0, stream>>>(vA, uB, vB);
    k_advect_d<<<gD, blk, 0, stream>>>(dA, uB, vB, out);
}

// Round 10
// 296.021 us; speedup vs baseline: 1.1531x; 1.1531x over previous
//
#include <hip/hip_runtime.h>

#define HH 2048
#define WW 2048
constexpr float DT = 0.01f;
constexpr float VISC = 0.001f;

// ---------------------------------------------------------------- bilerp ----
__device__ __forceinline__ float bilerp(const float* __restrict__ f, int h, int w,
                                        float y, float x) {
    int x0 = (int)floorf(x);
    int y0 = (int)floorf(y);
    int x1 = x0 + 1, y1 = y0 + 1;
    x0 = min(max(x0, 0), w - 1);
    x1 = min(max(x1, 0), w - 1);
    y0 = min(max(y0, 0), h - 1);
    y1 = min(max(y1, 0), h - 1);
    float x0f = (float)x0, x1f = (float)x1, y0f = (float)y0, y1f = (float)y1;
    float wa = (x1f - x) * (y1f - y);
    float wb = (x - x0f) * (y1f - y);
    float wc = (x1f - x) * (y - y0f);
    float wd = (x - x0f) * (y - y0f);
    return wa * f[y0 * w + x0] + wb * f[y0 * w + x1] +
           wc * f[y1 * w + x0] + wd * f[y1 * w + x1];
}

// ------------------------------------------ fused front, 2D LDS tiled -------
// Tile: 64 cols x 16 rows per 256-thread block. Stage raw u, v+force, den
// (19 rows x 72 cols, clamped at domain edges so plain +/-1 indexing
// reproduces the reference's edge clamps). Compute diffused u (rows i,i+1),
// diffused v (cols j..j+4), diffused d, and divergence from LDS only.
// All LDS reads are aligned b128; lf/rt come from neighbor-chunk lanes.
#define TX 64
#define TY 16
#define NR 19   // staged rows: r0-1 .. r0+17
#define SW 72   // LDS row stride in words; staged cols: x0-4 .. x0+67
#define NC 18   // float4 chunks per staged row

__global__ __launch_bounds__(256) void k_front(
    const float* __restrict__ u, const float* __restrict__ v,
    const float* __restrict__ den, float* __restrict__ ud,
    float* __restrict__ vd, float* __restrict__ dd, float* __restrict__ dv) {
    __shared__ float su[NR * SW];
    __shared__ float svf[NR * SW];
    __shared__ float sden[NR * SW];

    const int t = threadIdx.x;
    const int x0 = blockIdx.x * TX;
    const int r0 = blockIdx.y * TY;

    // ---- stage (clamped) ----
    for (int idx = t; idx < NR * NC; idx += 256) {
        const int lr = idx / NC;
        const int cx = idx - lr * NC;
        const int gy = r0 - 1 + lr;
        const int gx = x0 - 4 + cx * 4;
        const int lofs = lr * SW + cx * 4;
        const bool xin = (gx >= 0) && (gx + 3 < WW);

        // u: rows [0,HH], cols [0,WW-1]
        if (xin && gy >= 0 && gy <= HH) {
            *reinterpret_cast<float4*>(&su[lofs]) =
                *reinterpret_cast<const float4*>(u + (size_t)gy * WW + gx);
        } else {
            const int gyc = min(max(gy, 0), HH);
            #pragma unroll
            for (int e = 0; e < 4; ++e) {
                const int gxc = min(max(gx + e, 0), WW - 1);
                su[lofs + e] = u[(size_t)gyc * WW + gxc];
            }
        }

        // vf = v + DT*(den*0.1) for col<WW: rows [0,HH-1], cols [0,WW]
        {
            const int gyc = min(max(gy, 0), HH - 1);
            if (xin) {
                float4 vv = *reinterpret_cast<const float4*>(
                    v + (size_t)gyc * (WW + 1) + gx);
                const float4 dn4 = *reinterpret_cast<const float4*>(
                    den + (size_t)gyc * WW + gx);
                vv.x += DT * (dn4.x * 0.1f);
                vv.y += DT * (dn4.y * 0.1f);
                vv.z += DT * (dn4.z * 0.1f);
                vv.w += DT * (dn4.w * 0.1f);
                *reinterpret_cast<float4*>(&svf[lofs]) = vv;
            } else {
                #pragma unroll
                for (int e = 0; e < 4; ++e) {
                    const int gxc = min(max(gx + e, 0), WW);
                    float val = v[(size_t)gyc * (WW + 1) + gxc];
                    if (gxc < WW) val += DT * (den[(size_t)gyc * WW + gxc] * 0.1f);
                    svf[lofs + e] = val;
                }
            }
        }

        // den: rows [0,HH-1], cols [0,WW-1]
        {
            const int gyc = min(max(gy, 0), HH - 1);
            if (xin) {
                *reinterpret_cast<float4*>(&sden[lofs]) =
                    *reinterpret_cast<const float4*>(den + (size_t)gyc * WW + gx);
            } else {
                #pragma unroll
                for (int e = 0; e < 4; ++e) {
                    const int gxc = min(max(gx + e, 0), WW - 1);
                    sden[lofs + e] = den[(size_t)gyc * WW + gxc];
                }
            }
        }
    }
    __syncthreads();

    // ---- compute ----
    const int tx = t & 15, ty = t >> 4;
    const int i = r0 + ty;            // output row
    const int j = x0 + tx * 4;        // output col base
    const int lr = ty + 1;            // LDS row of i
    const int lc = 4 + tx * 4;        // LDS col of j

    #define LD4(s, r, c) (*reinterpret_cast<const float4*>(&(s)[(r) * SW + (c)]))

    // u rows i-1 .. i+2 plus L/R neighbors of rows i, i+1
    const float4 um  = LD4(su, lr - 1, lc);
    const float4 uc  = LD4(su, lr,     lc);
    const float4 up1 = LD4(su, lr + 1, lc);
    const float4 up2 = LD4(su, lr + 2, lc);
    const float4 uLc = LD4(su, lr,     lc - 4), uRc = LD4(su, lr,     lc + 4);
    const float4 uLn = LD4(su, lr + 1, lc - 4), uRn = LD4(su, lr + 1, lc + 4);

    // diffused u at (i, j..j+3); lap order: (((up+dn)+lf)+rt) - 4c
    float udA[4], udB[4];
    {
        const float lf[4] = {uLc.w, uc.x, uc.y, uc.z};
        const float rt[4] = {uc.y, uc.z, uc.w, uRc.x};
        const float cc[4] = {uc.x, uc.y, uc.z, uc.w};
        const float uu[4] = {um.x, um.y, um.z, um.w};
        const float dd_[4] = {up1.x, up1.y, up1.z, up1.w};
        #pragma unroll
        for (int e = 0; e < 4; ++e) {
            const float lap = (((uu[e] + dd_[e]) + lf[e]) + rt[e]) - 4.0f * cc[e];
            udA[e] = cc[e] + (DT * VISC) * lap;
        }
    }
    // diffused u at (i+1, j..j+3)
    {
        const float lf[4] = {uLn.w, up1.x, up1.y, up1.z};
        const float rt[4] = {up1.y, up1.z, up1.w, uRn.x};
        const float cc[4] = {up1.x, up1.y, up1.z, up1.w};
        const float uu[4] = {uc.x, uc.y, uc.z, uc.w};
        const float dd_[4] = {up2.x, up2.y, up2.z, up2.w};
        #pragma unroll
        for (int e = 0; e < 4; ++e) {
            const float lap = (((uu[e] + dd_[e]) + lf[e]) + rt[e]) - 4.0f * cc[e];
            udB[e] = cc[e] + (DT * VISC) * lap;
        }
    }

    // v (forced) rows i-1..i+1, center + R(rows i-1..i+1) + L(row i)
    const float4 vm  = LD4(svf, lr - 1, lc);
    const float4 vc  = LD4(svf, lr,     lc);
    const float4 vp  = LD4(svf, lr + 1, lc);
    const float4 vmR = LD4(svf, lr - 1, lc + 4);
    const float4 vcR = LD4(svf, lr,     lc + 4);
    const float4 vpR = LD4(svf, lr + 1, lc + 4);
    const float4 vcL = LD4(svf, lr,     lc - 4);

    float vdv[5];
    {
        const float lf[4] = {vcL.w, vc.x, vc.y, vc.z};
        const float rt[4] = {vc.y, vc.z, vc.w, vcR.x};
        const float cc[4] = {vc.x, vc.y, vc.z, vc.w};
        const float uu[4] = {vm.x, vm.y, vm.z, vm.w};
        const float dn[4] = {vp.x, vp.y, vp.z, vp.w};
        #pragma unroll
        for (int e = 0; e < 4; ++e) {
            const float lap = (((uu[e] + dn[e]) + lf[e]) + rt[e]) - 4.0f * cc[e];
            vdv[e] = cc[e] + (DT * VISC) * lap;
        }
        // col j+4
        const float lap4 = (((vmR.x + vpR.x) + vc.w) + vcR.y) - 4.0f * vcR.x;
        vdv[4] = vcR.x + (DT * VISC) * lap4;
    }

    // den rows i-1..i+1, center + L/R (row i)
    const float4 dm  = LD4(sden, lr - 1, lc);
    const float4 dc  = LD4(sden, lr,     lc);
    const float4 dp  = LD4(sden, lr + 1, lc);
    const float4 dcL = LD4(sden, lr,     lc - 4);
    const float4 dcR = LD4(sden, lr,     lc + 4);

    float4 ddv;
    {
        const float lf[4] = {dcL.w, dc.x, dc.y, dc.z};
        const float rt[4] = {dc.y, dc.z, dc.w, dcR.x};
        const float cc[4] = {dc.x, dc.y, dc.z, dc.w};
        const float uu[4] = {dm.x, dm.y, dm.z, dm.w};
        const float dn[4] = {dp.x, dp.y, dp.z, dp.w};
        float o[4];
        #pragma unroll
        for (int e = 0; e < 4; ++e) {
            const float lap = (((uu[e] + dn[e]) + lf[e]) + rt[e]) - 4.0f * cc[e];
            o[e] = cc[e] + (DT * (VISC * 0.1f)) * lap;
        }
        ddv = make_float4(o[0], o[1], o[2], o[3]);
    }

    // ---- writes ----
    *reinterpret_cast<float4*>(ud + (size_t)i * WW + j) =
        make_float4(udA[0], udA[1], udA[2], udA[3]);
    if (ty == TY - 1 && r0 + TY == HH)   // u's extra last row (row HH)
        *reinterpret_cast<float4*>(ud + (size_t)HH * WW + j) =
            make_float4(udB[0], udB[1], udB[2], udB[3]);

    const size_t vb = (size_t)i * (WW + 1) + j;
    vd[vb + 0] = vdv[0]; vd[vb + 1] = vdv[1];
    vd[vb + 2] = vdv[2]; vd[vb + 3] = vdv[3];
    if (tx == 15 && x0 + TX == WW) vd[vb + 4] = vdv[4];  // v's last column

    *reinterpret_cast<float4*>(dd + (size_t)i * WW + j) = ddv;

    // div = (((ud(i+1)-ud(i)) + vd(j+1)) - vd(j)) / DT
    float4 dvv;
    dvv.x = (((udB[0] - udA[0]) + vdv[1]) - vdv[0]) / DT;
    dvv.y = (((udB[1] - udA[1]) + vdv[2]) - vdv[1]) / DT;
    dvv.z = (((udB[2] - udA[2]) + vdv[3]) - vdv[2]) / DT;
    dvv.w = (((udB[3] - udA[3]) + vdv[4]) - vdv[3]) / DT;
    *reinterpret_cast<float4*>(dv + (size_t)i * WW + j) = dvv;
    #undef LD4
}

// ---------------------------------------------------- fused Jacobi (K=4) ----
#define TILE 56
#define KF 4
#define LW 64

__global__ __launch_bounds__(256) void k_jacobi_fused(
    const float* __restrict__ pin_g, const float* __restrict__ div_g,
    float* __restrict__ pout_g, int first) {
    __shared__ float pA[LW * LW];
    __shared__ float pB[LW * LW];

    const int t = threadIdx.x;
    const int gx0 = blockIdx.x * TILE - KF;
    const int gy0 = blockIdx.y * TILE - KF;

    float dreg[16];

    #pragma unroll
    for (int c = 0; c < 4; ++c)
        reinterpret_cast<float4*>(pB)[c * 256 + t] = make_float4(0.f, 0.f, 0.f, 0.f);

    #pragma unroll
    for (int c = 0; c < 4; ++c) {
        const int ci = c * 256 + t;
        const int y = ci >> 4;
        const int x = (ci & 15) * 4;
        const int gy = gy0 + y;
        const int gxb = gx0 + x;
        float4 pv = make_float4(0.f, 0.f, 0.f, 0.f);
        float4 dv4 = make_float4(0.f, 0.f, 0.f, 0.f);
        const bool rowin = (gy >= 0) && (gy < HH);
        if (rowin && gxb >= 0 && gxb + 3 < WW) {
            const size_t g = (size_t)gy * WW + gxb;
            dv4 = *reinterpret_cast<const float4*>(div_g + g);
            if (!first) pv = *reinterpret_cast<const float4*>(pin_g + g);
        } else if (rowin) {
            #pragma unroll
            for (int e = 0; e < 4; ++e) {
                const int gx = gxb + e;
                if (gx >= 0 && gx < WW) {
                    const size_t g = (size_t)gy * WW + gx;
                    (&dv4.x)[e] = div_g[g];
                    if (!first) (&pv.x)[e] = pin_g[g];
                }
            }
        }
        *reinterpret_cast<float4*>(&pA[y * LW + x]) = pv;
        dreg[c * 4 + 0] = dv4.x; dreg[c * 4 + 1] = dv4.y;
        dreg[c * 4 + 2] = dv4.z; dreg[c * 4 + 3] = dv4.w;
    }
    __syncthreads();

    float* pa = pA;
    float* pb = pB;
    for (int it = 0; it < KF; ++it) {
        #pragma unroll
        for (int c = 0; c < 4; ++c) {
            const int ci = c * 256 + t;
            const int y = ci >> 4;
            const int x = (ci & 15) * 4;
            if (y >= 1 && y <= LW - 2) {
                const float4 up = *reinterpret_cast<const float4*>(&pa[(y - 1) * LW + x]);
                const float4 dn = *reinterpret_cast<const float4*>(&pa[(y + 1) * LW + x]);
                const float4 ce = *reinterpret_cast<const float4*>(&pa[y * LW + x]);
                const float lf = (x > 0)      ? pa[y * LW + x - 1] : 0.f;
                const float rt = (x + 4 < LW) ? pa[y * LW + x + 4] : 0.f;
                const int gy = gy0 + y;
                const bool rowin = (gy > 0) && (gy < HH - 1);
                const int gxb = gx0 + x;
                float4 o;
                o.x = (rowin && gxb + 0 > 0 && gxb + 0 < WW - 1 && x + 0 > 0)
                      ? 0.25f * ((((up.x + dn.x) + lf) + ce.y) - dreg[c * 4 + 0]) : 0.f;
                o.y = (rowin && gxb + 1 > 0 && gxb + 1 < WW - 1)
                      ? 0.25f * ((((up.y + dn.y) + ce.x) + ce.z) - dreg[c * 4 + 1]) : 0.f;
                o.z = (rowin && gxb + 2 > 0 && gxb + 2 < WW - 1)
                      ? 0.25f * ((((up.z + dn.z) + ce.y) + ce.w) - dreg[c * 4 + 2]) : 0.f;
                o.w = (rowin && gxb + 3 > 0 && gxb + 3 < WW - 1 && x + 3 < LW - 1)
                      ? 0.25f * ((((up.w + dn.w) + ce.z) + rt) - dreg[c * 4 + 3]) : 0.f;
                *reinterpret_cast<float4*>(&pb[y * LW + x]) = o;
            }
        }
        __syncthreads();
        float* tmp = pa; pa = pb; pb = tmp;
    }

    #pragma unroll
    for (int c = 0; c < 4; ++c) {
        const int ci = c * 256 + t;
        const int y = ci >> 4;
        const int x = (ci & 15) * 4;
        if (y >= KF && y < KF + TILE && x >= KF && x < KF + TILE) {
            const int gy = gy0 + y;
            const int gxb = gx0 + x;
            if (gy < HH) {
                if (gxb + 3 < WW) {
                    *reinterpret_cast<float4*>(pout_g + (size_t)gy * WW + gxb) =
                        *reinterpret_cast<const float4*>(&pa[y * LW + x]);
                } else {
                    #pragma unroll
                    for (int e = 0; e < 4; ++e) {
                        const int gx = gxb + e;
                        if (gx < WW) pout_g[(size_t)gy * WW + gx] = pa[y * LW + x + e];
                    }
                }
            }
        }
    }
}

// ----------------------------------------------------- fused projection -----
__global__ __launch_bounds__(256) void k_project(
    float* __restrict__ u, float* __restrict__ v, const float* __restrict__ p) {
    const int j0 = (blockIdx.x * 256 + threadIdx.x) * 4;
    const int i = blockIdx.y;
    if (j0 >= WW) return;

    const float4 pc = *reinterpret_cast<const float4*>(p + (size_t)i * WW + j0);

    if (i >= 1) {
        const float4 pm = *reinterpret_cast<const float4*>(p + (size_t)(i - 1) * WW + j0);
        float4 uv = *reinterpret_cast<float4*>(u + (size_t)i * WW + j0);
        uv.x -= DT * (pc.x - pm.x);
        uv.y -= DT * (pc.y - pm.y);
        uv.z -= DT * (pc.z - pm.z);
        uv.w -= DT * (pc.w - pm.w);
        *reinterpret_cast<float4*>(u + (size_t)i * WW + j0) = uv;
    }

    const float pl = (j0 > 0) ? p[(size_t)i * WW + j0 - 1] : 0.f;
    const size_t vb = (size_t)i * (WW + 1) + j0;
    if (j0 > 0) v[vb + 0] -= DT * (pc.x - pl);
    v[vb + 1] -= DT * (pc.y - pc.x);
    v[vb + 2] -= DT * (pc.z - pc.y);
    if (j0 + 3 <= WW - 1) v[vb + 3] -= DT * (pc.w - pc.z);
}

// ---------------------------------------------------------------- advect ----
__global__ void k_advect_u(const float* __restrict__ uf, const float* __restrict__ vf,
                           float* __restrict__ out) {
    int j = blockIdx.x * blockDim.x + threadIdx.x;
    int i = blockIdx.y;
    const int h = HH + 1, w = WW;
    if (j >= w) return;
    float X = (float)j, Y = (float)i;
    float x_u = fminf(fmaxf(X + 0.5f, 0.0f), (float)(WW - 1));
    float u_i = bilerp(uf, HH + 1, WW, Y, x_u);
    float y_v = fminf(fmaxf(Y + 0.5f, 0.0f), (float)(HH - 1));
    float v_i = bilerp(vf, HH, WW + 1, y_v, X);
    float px = fminf(fmaxf(X - DT * u_i, 0.0f), (float)(w - 1));
    float py = fminf(fmaxf(Y - DT * v_i, 0.0f), (float)(h - 1));
    out[(size_t)i * w + j] = bilerp(uf, h, w, py, px);
}

__global__ void k_advect_v(const float* __restrict__ vf, const float* __restrict__ un,
                           float* __restrict__ out) {
    int j = blockIdx.x * blockDim.x + threadIdx.x;
    int i = blockIdx.y;
    const int h = HH, w = WW + 1;
    if (j >= w) return;
    float X = (float)j, Y = (float)i;
    float x_u = fminf(fmaxf(X + 0.5f, 0.0f), (float)(WW - 1));
    float u_i = bilerp(un, HH + 1, WW, Y, x_u);
    float y_v = fminf(fmaxf(Y + 0.5f, 0.0f), (float)(HH - 1));
    float v_i = bilerp(vf, HH, WW + 1, y_v, X);
    float px = fminf(fmaxf(X - DT * u_i, 0.0f), (float)(w - 1));
    float py = fminf(fmaxf(Y - DT * v_i, 0.0f), (float)(h - 1));
    out[(size_t)i * w + j] = bilerp(vf, h, w, py, px);
}

__global__ void k_advect_d(const float* __restrict__ df, const float* __restrict__ un,
                           const float* __restrict__ vn, float* __restrict__ out) {
    int j = blockIdx.x * blockDim.x + threadIdx.x;
    int i = blockIdx.y;
    const int h = HH, w = WW;
    if (j >= w) return;
    float X = (float)j, Y = (float)i;
    float x_u = fminf(fmaxf(X + 0.5f, 0.0f), (float)(WW - 1));
    float u_i = bilerp(un, HH + 1, WW, Y, x_u);
    float y_v = fminf(fmaxf(Y + 0.5f, 0.0f), (float)(HH - 1));
    float v_i = bilerp(vn, HH, WW + 1, y_v, X);
    float px = fminf(fmaxf(X - DT * u_i, 0.0f), (float)(w - 1));
    float py = fminf(fmaxf(Y - DT * v_i, 0.0f), (float)(h - 1));
    out[(size_t)i * w + j] = 0.995f * bilerp(df, h, w, py, px);
}

// ---------------------------------------------------------------- launch ----
extern "C" void kernel_launch(void* const* d_in, const int* in_sizes, int n_in,
                              void* d_out, int out_size, void* d_ws, size_t ws_size,
                              hipStream_t stream) {
    const float* u_in   = (const float*)d_in[0];
    const float* v_in   = (const float*)d_in[1];
    const float* den_in = (const float*)d_in[2];
    float* out = (float*)d_out;

    const size_t SZ_UV = (size_t)(HH + 1) * WW;
    const size_t SZ_D  = (size_t)HH * WW;

    float* ws = (float*)d_ws;
    float* uA = ws;  ws += SZ_UV;
    float* uB = ws;  ws += SZ_UV;
    float* vA = ws;  ws += SZ_UV;
    float* vB = ws;  ws += SZ_UV;
    float* dA = ws;  ws += SZ_D;
    float* dv = ws;  ws += SZ_D;
    float* p0 = ws;  ws += SZ_D;
    float* p1 = ws;  ws += SZ_D;

    dim3 blk(256, 1, 1);

    // fused diffuse(u,v,d) + divergence, 2D LDS tiled
    dim3 gF(WW / TX, HH / TY);  // 32 x 128
    k_front<<<gF, blk, 0, stream>>>(u_in, v_in, den_in, uA, vA, dA, dv);

    // 20 Jacobi iterations = 5 launches x 4 fused (first starts from p=0).
    dim3 gJ((WW + TILE - 1) / TILE, (HH + TILE - 1) / TILE);  // 37 x 37
    k_jacobi_fused<<<gJ, blk, 0, stream>>>(dv /*unused*/, dv, p1, 1);
    float* pin = p1;
    float* pout = p0;
    for (int l = 1; l < 5; ++l) {
        k_jacobi_fused<<<gJ, blk, 0, stream>>>(pin, dv, pout, 0);
        float* t = pin; pin = pout; pout = t;
    }
    // final pressure in `pin`

    // fused projection
    dim3 gP(WW / (256 * 4), HH);  // (2, 2048)
    k_project<<<gP, blk, 0, stream>>>(uA, vA, pin);

    dim3 gU((WW + 255) / 256, HH + 1);
    dim3 gV((WW + 1 + 255) / 256, HH);
    dim3 gD((WW + 255) / 256, HH);
    k_advect_u<<<gU, blk, 0, stream>>>(uA, vA, uB);
    k_advect_v<<<gV, blk, 0, stream>>>(vA, uB, vB);
    k_advect_d<<<gD, blk, 0, stream>>>(dA, uB, vB, out);
}